// Round 6
// baseline (642.567 us; speedup 1.0000x reference)
//
#include <hip/hip_runtime.h>
#include <hip/hip_bf16.h>
#include <math.h>

// Problem constants
#define T_     1024
#define DIM_   2048
#define H_     16
#define QLR_   1024
#define KVLR_  512
#define NOPE_  128
#define ROPE_  64
#define VD_    128
#define QKD_   192   // NOPE+ROPE
#define IH_    16
#define ID_    128
#define TOPK_  256
#define CKV_   576   // KVLR + ROPE

#define SCALE_W    0.022097086912079608f   // IH^-0.5 * ID^-0.5
#define SCALE_LOG  0.07216878364870323f    // QKD^-0.5

typedef short bfrag __attribute__((ext_vector_type(8)));   // 8 bf16 = 4 VGPRs
typedef float ffrag __attribute__((ext_vector_type(4)));   // 4 fp32 acc

__device__ __forceinline__ unsigned short f2bf(float f) {
    union { __hip_bfloat16 h; unsigned short u; } c; c.h = __float2bfloat16(f); return c.u;
}
__device__ __forceinline__ float bf2f(unsigned short u) {
    union { unsigned short u; __hip_bfloat16 h; } c; c.u = u; return __bfloat162float(c.h);
}

// ---------------------------------------------------------------------------
// fp32 -> bf16 cast, optional hi/lo split and per-row/col scaling.
// ---------------------------------------------------------------------------
__global__ __launch_bounds__(256) void cast_hl_k(
    const float* __restrict__ in, unsigned short* __restrict__ hi,
    unsigned short* __restrict__ lo, long n,
    const float* __restrict__ colw, const float* __restrict__ rowscale, int Kc)
{
    long base = ((long)blockIdx.x * 256 + threadIdx.x) * 4;
    if (base >= n) return;
    float4 v = *(const float4*)(in + base);
    float s[4] = {v.x, v.y, v.z, v.w};
    if (colw) {
        int col = (int)(base % Kc);
        float4 cw = *(const float4*)(colw + col);
        s[0] *= cw.x; s[1] *= cw.y; s[2] *= cw.z; s[3] *= cw.w;
    }
    if (rowscale) {
        float r = rowscale[base / Kc];
        s[0] *= r; s[1] *= r; s[2] *= r; s[3] *= r;
    }
    ushort4 h4;
    h4.x = f2bf(s[0]); h4.y = f2bf(s[1]); h4.z = f2bf(s[2]); h4.w = f2bf(s[3]);
    *(ushort4*)(hi + base) = h4;
    if (lo) {
        ushort4 l4;
        l4.x = f2bf(s[0] - bf2f(h4.x));
        l4.y = f2bf(s[1] - bf2f(h4.y));
        l4.z = f2bf(s[2] - bf2f(h4.z));
        l4.w = f2bf(s[3] - bf2f(h4.w));
        *(ushort4*)(lo + base) = l4;
    }
}

// ---------------------------------------------------------------------------
// Transpose-cast w_k: wkT[h][c][d] = bf16(wkv_b[(h*256+d)*512 + c]), d<128, c<512
// ---------------------------------------------------------------------------
__global__ __launch_bounds__(256) void tcast_k(const float* __restrict__ in,
                                               unsigned short* __restrict__ out)
{
    int h = blockIdx.z, c0 = blockIdx.x * 32, d0 = blockIdx.y * 32;
    __shared__ float t[32][33];
    int tx = threadIdx.x & 31, ty = threadIdx.x >> 5;
    #pragma unroll
    for (int i = 0; i < 4; ++i)
        t[ty + i * 8][tx] = in[(long)(h * 256 + d0 + ty + i * 8) * 512 + c0 + tx];
    __syncthreads();
    #pragma unroll
    for (int i = 0; i < 4; ++i)
        out[((long)h * 512 + c0 + ty + i * 8) * 128 + d0 + tx] = f2bf(t[tx][ty + i * 8]);
}

// ---------------------------------------------------------------------------
// MFMA bf16 NT GEMM, 128x128 tile (batched q_nope_proj). Register-prefetch.
// ---------------------------------------------------------------------------
__global__ __launch_bounds__(256) void gemm_bt_mfma_k(
    const unsigned short* __restrict__ A, const unsigned short* __restrict__ B,
    float* __restrict__ C, long sA, long sB, long sC,
    int lda, int ldb, int ldc, int N, int K)
{
    A += (long)blockIdx.z * sA;
    B += (long)blockIdx.z * sB;
    C += (long)blockIdx.z * sC;
    __shared__ unsigned short As[128 * 40];
    __shared__ unsigned short Bs[128 * 40];
    const int tid = threadIdx.x;
    const int bm = blockIdx.y * 128, bn = blockIdx.x * 128;
    const int wave = tid >> 6, lane = tid & 63;
    const int wm = (wave >> 1) * 64, wn = (wave & 1) * 64;
    const int lm = lane & 15, quad = lane >> 4;

    ffrag acc[4][4];
    #pragma unroll
    for (int mi = 0; mi < 4; ++mi)
        #pragma unroll
        for (int ni = 0; ni < 4; ++ni)
            #pragma unroll
            for (int r = 0; r < 4; ++r) acc[mi][ni][r] = 0.f;

    const int srow = tid >> 1, shalf = tid & 1;
    const long aoff = (long)(bm + srow) * lda + shalf * 16;
    int brow = bn + srow; if (brow > N - 1) brow = N - 1;
    const long boff = (long)brow * ldb + shalf * 16;
    unsigned short* la = As + srow * 40 + shalf * 16;
    unsigned short* lb = Bs + srow * 40 + shalf * 16;

    uint4 va0 = *(const uint4*)(A + aoff);
    uint4 va1 = *(const uint4*)(A + aoff + 8);
    uint4 vb0 = *(const uint4*)(B + boff);
    uint4 vb1 = *(const uint4*)(B + boff + 8);

    for (int k0 = 0; k0 < K; k0 += 32) {
        __syncthreads();
        *(uint4*)la = va0; *(uint4*)(la + 8) = va1;
        *(uint4*)lb = vb0; *(uint4*)(lb + 8) = vb1;
        __syncthreads();
        if (k0 + 32 < K) {
            va0 = *(const uint4*)(A + aoff + k0 + 32);
            va1 = *(const uint4*)(A + aoff + k0 + 40);
            vb0 = *(const uint4*)(B + boff + k0 + 32);
            vb1 = *(const uint4*)(B + boff + k0 + 40);
        }
        bfrag af[4], bf[4];
        #pragma unroll
        for (int mi = 0; mi < 4; ++mi)
            af[mi] = *(const bfrag*)(As + (wm + mi * 16 + lm) * 40 + quad * 8);
        #pragma unroll
        for (int ni = 0; ni < 4; ++ni)
            bf[ni] = *(const bfrag*)(Bs + (wn + ni * 16 + lm) * 40 + quad * 8);
        #pragma unroll
        for (int mi = 0; mi < 4; ++mi)
            #pragma unroll
            for (int ni = 0; ni < 4; ++ni)
                acc[mi][ni] = __builtin_amdgcn_mfma_f32_16x16x32_bf16(
                    af[mi], bf[ni], acc[mi][ni], 0, 0, 0);
    }

    #pragma unroll
    for (int mi = 0; mi < 4; ++mi)
        #pragma unroll
        for (int ni = 0; ni < 4; ++ni) {
            int n = bn + wn + ni * 16 + lm;
            if (n < N) {
                int mb = bm + wm + mi * 16 + quad * 4;
                #pragma unroll
                for (int r = 0; r < 4; ++r)
                    C[(long)(mb + r) * ldc + n] = acc[mi][ni][r];
            }
        }
}

// ---------------------------------------------------------------------------
// MFMA bf16 NT GEMM, 64x64 tile. obf=1 -> write bf16 C. Register-prefetch.
// ---------------------------------------------------------------------------
__global__ __launch_bounds__(256) void gemm_bt64_k(
    const unsigned short* __restrict__ A, const unsigned short* __restrict__ B,
    void* __restrict__ Cv, long sA, long sB, long sC,
    int lda, int ldb, int ldc, int N, int K, int obf)
{
    A += (long)blockIdx.z * sA;
    B += (long)blockIdx.z * sB;
    __shared__ unsigned short As[64 * 40];
    __shared__ unsigned short Bs[64 * 40];
    const int tid = threadIdx.x;
    const int bm = blockIdx.y * 64, bn = blockIdx.x * 64;
    const int wave = tid >> 6, lane = tid & 63;
    const int wm = (wave >> 1) * 32, wn = (wave & 1) * 32;
    const int lm = lane & 15, quad = lane >> 4;

    ffrag acc[2][2];
    #pragma unroll
    for (int mi = 0; mi < 2; ++mi)
        #pragma unroll
        for (int ni = 0; ni < 2; ++ni)
            #pragma unroll
            for (int r = 0; r < 4; ++r) acc[mi][ni][r] = 0.f;

    const int srow = tid >> 2, schunk = tid & 3;
    const long aoff = (long)(bm + srow) * lda + schunk * 8;
    int brow = bn + srow; if (brow > N - 1) brow = N - 1;
    const long boff = (long)brow * ldb + schunk * 8;
    unsigned short* la = As + srow * 40 + schunk * 8;
    unsigned short* lb = Bs + srow * 40 + schunk * 8;

    uint4 va = *(const uint4*)(A + aoff);
    uint4 vb = *(const uint4*)(B + boff);

    for (int k0 = 0; k0 < K; k0 += 32) {
        __syncthreads();
        *(uint4*)la = va;
        *(uint4*)lb = vb;
        __syncthreads();
        if (k0 + 32 < K) {
            va = *(const uint4*)(A + aoff + k0 + 32);
            vb = *(const uint4*)(B + boff + k0 + 32);
        }
        bfrag af[2], bf[2];
        #pragma unroll
        for (int mi = 0; mi < 2; ++mi)
            af[mi] = *(const bfrag*)(As + (wm + mi * 16 + lm) * 40 + quad * 8);
        #pragma unroll
        for (int ni = 0; ni < 2; ++ni)
            bf[ni] = *(const bfrag*)(Bs + (wn + ni * 16 + lm) * 40 + quad * 8);
        #pragma unroll
        for (int mi = 0; mi < 2; ++mi)
            #pragma unroll
            for (int ni = 0; ni < 2; ++ni)
                acc[mi][ni] = __builtin_amdgcn_mfma_f32_16x16x32_bf16(
                    af[mi], bf[ni], acc[mi][ni], 0, 0, 0);
    }

    #pragma unroll
    for (int mi = 0; mi < 2; ++mi)
        #pragma unroll
        for (int ni = 0; ni < 2; ++ni) {
            int n = bn + wn + ni * 16 + lm;
            if (n < N) {
                int mb = bm + wm + mi * 16 + quad * 4;
                if (obf) {
                    unsigned short* C = (unsigned short*)Cv + (long)blockIdx.z * sC;
                    #pragma unroll
                    for (int r = 0; r < 4; ++r)
                        C[(long)(mb + r) * ldc + n] = f2bf(acc[mi][ni][r]);
                } else {
                    float* C = (float*)Cv + (long)blockIdx.z * sC;
                    #pragma unroll
                    for (int r = 0; r < 4; ++r)
                        C[(long)(mb + r) * ldc + n] = acc[mi][ni][r];
                }
            }
        }
}

// ---------------------------------------------------------------------------
// Fused bf16x3 NT GEMM, 64x64 tile: C = Ah.Bh^T + Ah.Bl^T + Al.Bh^T
// Register-prefetch pipelined.
// ---------------------------------------------------------------------------
__global__ __launch_bounds__(256) void gemm3_bt64_k(
    const unsigned short* __restrict__ Ah, const unsigned short* __restrict__ Al,
    const unsigned short* __restrict__ Bh, const unsigned short* __restrict__ Bl,
    float* __restrict__ C, int lda, int ldb, int ldc, int K)
{
    __shared__ unsigned short Ahs[64 * 40], Als[64 * 40], Bhs[64 * 40], Bls[64 * 40];
    const int tid = threadIdx.x;
    const int bm = blockIdx.y * 64, bn = blockIdx.x * 64;
    const int wave = tid >> 6, lane = tid & 63;
    const int wm = (wave >> 1) * 32, wn = (wave & 1) * 32;
    const int lm = lane & 15, quad = lane >> 4;

    ffrag acc[2][2];
    #pragma unroll
    for (int mi = 0; mi < 2; ++mi)
        #pragma unroll
        for (int ni = 0; ni < 2; ++ni)
            #pragma unroll
            for (int r = 0; r < 4; ++r) acc[mi][ni][r] = 0.f;

    const int srow = tid >> 2, schunk = tid & 3;
    const long aoff = (long)(bm + srow) * lda + schunk * 8;
    const long boff = (long)(bn + srow) * ldb + schunk * 8;
    const int loff = srow * 40 + schunk * 8;

    uint4 vah = *(const uint4*)(Ah + aoff);
    uint4 val = *(const uint4*)(Al + aoff);
    uint4 vbh = *(const uint4*)(Bh + boff);
    uint4 vbl = *(const uint4*)(Bl + boff);

    for (int k0 = 0; k0 < K; k0 += 32) {
        __syncthreads();
        *(uint4*)(Ahs + loff) = vah;
        *(uint4*)(Als + loff) = val;
        *(uint4*)(Bhs + loff) = vbh;
        *(uint4*)(Bls + loff) = vbl;
        __syncthreads();
        if (k0 + 32 < K) {
            vah = *(const uint4*)(Ah + aoff + k0 + 32);
            val = *(const uint4*)(Al + aoff + k0 + 32);
            vbh = *(const uint4*)(Bh + boff + k0 + 32);
            vbl = *(const uint4*)(Bl + boff + k0 + 32);
        }
        bfrag ah[2], al[2], bh[2], bl[2];
        #pragma unroll
        for (int mi = 0; mi < 2; ++mi) {
            ah[mi] = *(const bfrag*)(Ahs + (wm + mi * 16 + lm) * 40 + quad * 8);
            al[mi] = *(const bfrag*)(Als + (wm + mi * 16 + lm) * 40 + quad * 8);
        }
        #pragma unroll
        for (int ni = 0; ni < 2; ++ni) {
            bh[ni] = *(const bfrag*)(Bhs + (wn + ni * 16 + lm) * 40 + quad * 8);
            bl[ni] = *(const bfrag*)(Bls + (wn + ni * 16 + lm) * 40 + quad * 8);
        }
        #pragma unroll
        for (int mi = 0; mi < 2; ++mi)
            #pragma unroll
            for (int ni = 0; ni < 2; ++ni) {
                acc[mi][ni] = __builtin_amdgcn_mfma_f32_16x16x32_bf16(ah[mi], bh[ni], acc[mi][ni], 0, 0, 0);
                acc[mi][ni] = __builtin_amdgcn_mfma_f32_16x16x32_bf16(ah[mi], bl[ni], acc[mi][ni], 0, 0, 0);
                acc[mi][ni] = __builtin_amdgcn_mfma_f32_16x16x32_bf16(al[mi], bh[ni], acc[mi][ni], 0, 0, 0);
            }
    }

    #pragma unroll
    for (int mi = 0; mi < 2; ++mi)
        #pragma unroll
        for (int ni = 0; ni < 2; ++ni) {
            int n = bn + wn + ni * 16 + lm;
            int mb = bm + wm + mi * 16 + quad * 4;
            #pragma unroll
            for (int r = 0; r < 4; ++r)
                C[(long)(mb + r) * ldc + n] = acc[mi][ni][r];
        }
}

// ---------------------------------------------------------------------------
// Fused wtok: wtok[t,h] = dot(x[t,:], wproj[h,:]) * SCALE_W  (fp32)
// ---------------------------------------------------------------------------
__global__ __launch_bounds__(256) void wtok_k(const float* __restrict__ x,
    const float* __restrict__ wproj, float* __restrict__ wtok)
{
    int t = blockIdx.x, tid = threadIdx.x;
    __shared__ float xs[DIM_];
    for (int c = tid; c < DIM_; c += 256) xs[c] = x[(long)t * DIM_ + c];
    __syncthreads();
    int wave = tid >> 6, lane = tid & 63;
    #pragma unroll
    for (int i = 0; i < 4; ++i) {
        int h = wave * 4 + i;
        float s = 0.f;
        for (int c = lane; c < DIM_; c += 64) s += xs[c] * wproj[(long)h * DIM_ + c];
        for (int off = 32; off; off >>= 1) s += __shfl_xor(s, off, 64);
        if (lane == 0) wtok[(long)t * IH_ + h] = s * SCALE_W;
    }
}

// ---------------------------------------------------------------------------
__global__ __launch_bounds__(256) void rstd_k(const float* __restrict__ qr, float* __restrict__ rstd)
{
    int t = blockIdx.x, tid = threadIdx.x;
    float s = 0.f;
    for (int c = tid; c < QLR_; c += 256) { float v = qr[(long)t * QLR_ + c]; s += v * v; }
    __shared__ float red[256];
    red[tid] = s; __syncthreads();
    for (int off = 128; off; off >>= 1) { if (tid < off) red[tid] += red[tid + off]; __syncthreads(); }
    if (tid == 0) rstd[t] = rsqrtf(red[0] / (float)QLR_ + 1e-6f);
}

// ---------------------------------------------------------------------------
__device__ __forceinline__ void rope_rotate_128(float* s, float* w2, int tid, int t,
    const float* __restrict__ cosb, const float* __restrict__ sinb)
{
    float n1 = 0.f, n2 = 0.f;
    if (tid < 32) {
        float x1 = s[tid], x2 = s[tid + 32];
        float c = cosb[t * 32 + tid], sn = sinb[t * 32 + tid];
        n1 = x1 * c - x2 * sn;
        n2 = x1 * sn + x2 * c;
    }
    __syncthreads();
    if (tid < 32) { s[tid] = n1; s[tid + 32] = n2; }
    __syncthreads();
    const int g = tid >> 6, p = tid & 63;
    w2[tid] = s[((1 - g) << 6) + p];
    __syncthreads();
    #pragma unroll
    for (int h = 1; h < 64; h <<= 1) {
        float a = w2[tid], b = w2[(g << 6) + (p ^ h)];
        __syncthreads();
        w2[tid] = (p & h) ? (b - a) : (a + b);
        __syncthreads();
    }
}

__global__ __launch_bounds__(128) void transform_iq_k(float* __restrict__ iq,
    const float* __restrict__ cosb, const float* __restrict__ sinb)
{
    int row = blockIdx.x;
    int t = row / IH_;
    int tid = threadIdx.x;
    __shared__ float s[128], w2[128];
    s[tid] = iq[(long)row * 128 + tid];
    __syncthreads();
    rope_rotate_128(s, w2, tid, t, cosb, sinb);
    iq[(long)row * 128 + tid] = w2[tid];
}

__global__ __launch_bounds__(128) void transform_ik_k(float* __restrict__ ik,
    const float* __restrict__ knw, const float* __restrict__ knb,
    const float* __restrict__ cosb, const float* __restrict__ sinb)
{
    int row = blockIdx.x;
    int t = row / IH_;
    int tid = threadIdx.x;
    __shared__ float s[128], w2[128], red[128];
    float v = ik[(long)row * 128 + tid];
    red[tid] = v; __syncthreads();
    for (int off = 64; off; off >>= 1) { if (tid < off) red[tid] += red[tid + off]; __syncthreads(); }
    float m = red[0] / 128.f; __syncthreads();
    float d = v - m;
    red[tid] = d * d; __syncthreads();
    for (int off = 64; off; off >>= 1) { if (tid < off) red[tid] += red[tid + off]; __syncthreads(); }
    float var = red[0] / 128.f;
    s[tid] = d * rsqrtf(var + 1e-5f) * knw[tid] + knb[tid];
    __syncthreads();
    rope_rotate_128(s, w2, tid, t, cosb, sinb);
    ik[(long)row * 128 + tid] = w2[tid];
}

__global__ __launch_bounds__(256) void transform_kv_k(const float* __restrict__ kva,
    float* __restrict__ kvkey, const float* __restrict__ kvnw,
    const float* __restrict__ cosb, const float* __restrict__ sinb)
{
    int t = blockIdx.x, tid = threadIdx.x;
    const float* a = kva + (long)t * CKV_;
    float* o = kvkey + (long)t * CKV_;
    float v0 = a[tid], v1 = a[tid + 256];
    __shared__ float red[256];
    __shared__ float rsh;
    red[tid] = v0 * v0 + v1 * v1; __syncthreads();
    for (int off = 128; off; off >>= 1) { if (tid < off) red[tid] += red[tid + off]; __syncthreads(); }
    if (tid == 0) rsh = rsqrtf(red[0] / (float)KVLR_ + 1e-6f);
    __syncthreads();
    float rs = rsh;
    o[tid]       = v0 * rs * kvnw[tid];
    o[tid + 256] = v1 * rs * kvnw[tid + 256];
    if (tid < 32) {
        float x1 = a[512 + tid], x2 = a[544 + tid];
        float c = cosb[t * 32 + tid], sn = sinb[t * 32 + tid];
        o[512 + tid] = x1 * c - x2 * sn;
        o[544 + tid] = x1 * sn + x2 * c;
    }
}

__global__ __launch_bounds__(64) void qpe_k(const float* __restrict__ q, float* __restrict__ qkey,
    const float* __restrict__ cosb, const float* __restrict__ sinb)
{
    int row = blockIdx.x * 2 + (threadIdx.x >> 5);
    int i = threadIdx.x & 31;
    int t = row / H_;
    const float* qp = q + (long)row * QKD_ + NOPE_;
    float x1 = qp[i], x2 = qp[i + 32];
    float c = cosb[t * 32 + i], sn = sinb[t * 32 + i];
    float* o = qkey + (long)row * CKV_ + 512;
    o[i]      = x1 * c - x2 * sn;
    o[i + 32] = x1 * sn + x2 * c;
}

// ---------------------------------------------------------------------------
// Indexer score (MFMA bf16x3), register-prefetch across (h,k0) steps.
// ---------------------------------------------------------------------------
__global__ __launch_bounds__(256) void score3_k(
    const unsigned short* __restrict__ iqh, const unsigned short* __restrict__ iql,
    const unsigned short* __restrict__ ikh, const unsigned short* __restrict__ ikl,
    const float* __restrict__ wtok, float* __restrict__ score)
{
    const int bt = blockIdx.y, bs = blockIdx.x;
    if (bs > bt) return;
    __shared__ unsigned short Ah[64 * 40], Al[64 * 40], Bh[64 * 40], Bl[64 * 40];
    __shared__ float wts[64][16];
    const int tid = threadIdx.x;
    const int wave = tid >> 6, lane = tid & 63;
    const int wm = (wave >> 1) * 32, wn = (wave & 1) * 32;
    const int lm = lane & 15, quad = lane >> 4;
    const int t0 = bt * 64, s0 = bs * 64;
    const int srow = tid >> 2, schunk = tid & 3;
    const int loff = srow * 40 + schunk * 8;

    for (int e = tid; e < 1024; e += 256)
        wts[e >> 4][e & 15] = wtok[(long)(t0 + (e >> 4)) * IH_ + (e & 15)];

    const long abase = (long)(t0 + srow) * 2048 + schunk * 8;
    const long bbase = (long)(s0 + srow) * 2048 + schunk * 8;

    uint4 pah = *(const uint4*)(iqh + abase);
    uint4 pal = *(const uint4*)(iql + abase);
    uint4 pbh = *(const uint4*)(ikh + bbase);
    uint4 pbl = *(const uint4*)(ikl + bbase);

    float accf[2][2][4] = {};

    for (int h = 0; h < IH_; ++h) {
        ffrag acch[2][2];
        #pragma unroll
        for (int mi = 0; mi < 2; ++mi)
            #pragma unroll
            for (int ni = 0; ni < 2; ++ni)
                #pragma unroll
                for (int r = 0; r < 4; ++r) acch[mi][ni][r] = 0.f;

        #pragma unroll
        for (int k0 = 0; k0 < ID_; k0 += 32) {
            __syncthreads();
            *(uint4*)(Ah + loff) = pah;
            *(uint4*)(Al + loff) = pal;
            *(uint4*)(Bh + loff) = pbh;
            *(uint4*)(Bl + loff) = pbl;
            __syncthreads();
            int step = h * 4 + (k0 >> 5) + 1;
            if (step < 64) {
                int off = (step >> 2) * 128 + (step & 3) * 32;
                pah = *(const uint4*)(iqh + abase + off);
                pal = *(const uint4*)(iql + abase + off);
                pbh = *(const uint4*)(ikh + bbase + off);
                pbl = *(const uint4*)(ikl + bbase + off);
            }
            bfrag ahf[2], alf[2], bhf[2], blf[2];
            #pragma unroll
            for (int mi = 0; mi < 2; ++mi) {
                ahf[mi] = *(const bfrag*)(Ah + (wm + mi * 16 + lm) * 40 + quad * 8);
                alf[mi] = *(const bfrag*)(Al + (wm + mi * 16 + lm) * 40 + quad * 8);
            }
            #pragma unroll
            for (int ni = 0; ni < 2; ++ni) {
                bhf[ni] = *(const bfrag*)(Bh + (wn + ni * 16 + lm) * 40 + quad * 8);
                blf[ni] = *(const bfrag*)(Bl + (wn + ni * 16 + lm) * 40 + quad * 8);
            }
            #pragma unroll
            for (int mi = 0; mi < 2; ++mi)
                #pragma unroll
                for (int ni = 0; ni < 2; ++ni) {
                    acch[mi][ni] = __builtin_amdgcn_mfma_f32_16x16x32_bf16(ahf[mi], bhf[ni], acch[mi][ni], 0, 0, 0);
                    acch[mi][ni] = __builtin_amdgcn_mfma_f32_16x16x32_bf16(ahf[mi], blf[ni], acch[mi][ni], 0, 0, 0);
                    acch[mi][ni] = __builtin_amdgcn_mfma_f32_16x16x32_bf16(alf[mi], bhf[ni], acch[mi][ni], 0, 0, 0);
                }
        }
        #pragma unroll
        for (int mi = 0; mi < 2; ++mi) {
            float wr[4];
            #pragma unroll
            for (int r = 0; r < 4; ++r) wr[r] = wts[wm + mi * 16 + quad * 4 + r][h];
            #pragma unroll
            for (int ni = 0; ni < 2; ++ni)
                #pragma unroll
                for (int r = 0; r < 4; ++r)
                    accf[mi][ni][r] += fmaxf(acch[mi][ni][r], 0.f) * wr[r];
        }
    }
    #pragma unroll
    for (int mi = 0; mi < 2; ++mi)
        #pragma unroll
        for (int ni = 0; ni < 2; ++ni) {
            int s = s0 + wn + ni * 16 + lm;
            int tb = t0 + wm + mi * 16 + quad * 4;
            #pragma unroll
            for (int r = 0; r < 4; ++r)
                score[(long)(tb + r) * T_ + s] = accf[mi][ni][r];
        }
}

// ---------------------------------------------------------------------------
// Top-256 per row via bitonic sort (ties -> lower index, matches jax top_k)
// ---------------------------------------------------------------------------
__global__ __launch_bounds__(512) void topk_k(const float* __restrict__ score, int* __restrict__ topk)
{
    int t = blockIdx.x, tid = threadIdx.x;
    __shared__ float v[1024];
    __shared__ int ix[1024];
    for (int i = tid; i < 1024; i += 512) {
        v[i] = (i <= t) ? score[(long)t * T_ + i] : -INFINITY;
        ix[i] = i;
    }
    __syncthreads();
    for (int k = 2; k <= 1024; k <<= 1) {
        for (int j = k >> 1; j > 0; j >>= 1) {
            for (int i = tid; i < 1024; i += 512) {
                int l = i ^ j;
                if (l > i) {
                    bool up = ((i & k) == 0);
                    float vi = v[i], vl = v[l];
                    int xi = ix[i], xl = ix[l];
                    bool iBetter = (vi > vl) || (vi == vl && xi < xl);
                    bool doSwap = up ? !iBetter : iBetter;
                    if (doSwap) { v[i] = vl; v[l] = vi; ix[i] = xl; ix[l] = xi; }
                }
            }
            __syncthreads();
        }
    }
    if (tid < 256) topk[(long)t * TOPK_ + tid] = ix[tid];
}

// ---------------------------------------------------------------------------
// Attention v4 (MFMA bf16): one block per token, 4 waves, ~49.7 KB LDS
// (3 blocks/CU), conflict-free VT stride 36, register-prefetch pipelining.
// LDS (ushort offsets): Qbf[16*584]@0; SelA[256*40]@9344 (Lg fp32 [16*260]
// overlays it after phase A); Pbf[16*264]@19584; VT[512*36]@0 (phase B,
// fits inside Qbf+SelA, below Pbf).
// ---------------------------------------------------------------------------
__global__ __launch_bounds__(256) void attn3_k(
    const float* __restrict__ qkey, const unsigned short* __restrict__ kvb,
    const int* __restrict__ topkp, unsigned short* __restrict__ olat)
{
    __shared__ unsigned short U[23808];
    __shared__ float red[16 * 17];
    __shared__ int kidx[256];
    unsigned short* Qbf  = U;                    // [16][584]
    unsigned short* SelA = U + 9344;             // [256][40]
    float*          Lg   = (float*)(U + 9344);   // [16][260] (after phase A)
    unsigned short* Pbf  = U + 19584;            // [16][264]
    unsigned short* VT   = U;                    // [512][36] (phase B)

    const int t = blockIdx.x, tid = threadIdx.x;
    const int wave = tid >> 6, lane = tid & 63;
    const int lm = lane & 15, quad = lane >> 4;

    kidx[tid] = topkp[(long)t * TOPK_ + tid];
    // stage + cast Q row: 9216 floats -> Qbf[16][584]
    const float4* q4 = (const float4*)(qkey + (long)t * (H_ * CKV_));
    #pragma unroll
    for (int rep = 0; rep < 9; ++rep) {
        int e4 = rep * 256 + tid;
        float4 v = q4[e4];
        int f = e4 * 4, h = f / CKV_, c = f - h * CKV_;
        ushort4 u4; u4.x = f2bf(v.x); u4.y = f2bf(v.y); u4.z = f2bf(v.z); u4.w = f2bf(v.w);
        *(ushort4*)(Qbf + h * 584 + c) = u4;
    }
    __syncthreads();

    // ---- Phase A: logits ----
    const int ukey = tid >> 2, uoff = (tid & 3) * 8;
    int myk[4];
    #pragma unroll
    for (int rep = 0; rep < 4; ++rep) myk[rep] = kidx[rep * 64 + ukey];

    uint4 pf[4];
    #pragma unroll
    for (int rep = 0; rep < 4; ++rep)
        pf[rep] = *(const uint4*)(kvb + (long)myk[rep] * CKV_ + uoff);

    ffrag acc[4];
    #pragma unroll
    for (int ni = 0; ni < 4; ++ni)
        #pragma unroll
        for (int r = 0; r < 4; ++r) acc[ni][r] = 0.f;

    for (int c0 = 0; c0 < CKV_; c0 += 32) {
        __syncthreads();
        #pragma unroll
        for (int rep = 0; rep < 4; ++rep)
            *(uint4*)(SelA + (rep * 64 + ukey) * 40 + uoff) = pf[rep];
        __syncthreads();
        if (c0 + 32 < CKV_) {
            #pragma unroll
            for (int rep = 0; rep < 4; ++rep)
                pf[rep] = *(const uint4*)(kvb + (long)myk[rep] * CKV_ + c0 + 32 + uoff);
        }
        bfrag af = *(const bfrag*)(Qbf + lm * 584 + c0 + quad * 8);
        #pragma unroll
        for (int ni = 0; ni < 4; ++ni) {
            bfrag bf = *(const bfrag*)(SelA + (wave * 64 + ni * 16 + lm) * 40 + quad * 8);
            acc[ni] = __builtin_amdgcn_mfma_f32_16x16x32_bf16(af, bf, acc[ni], 0, 0, 0);
        }
    }
    __syncthreads();
    // write logits (overlays SelA): D col=lane&15 (key), row=quad*4+r (head)
    #pragma unroll
    for (int ni = 0; ni < 4; ++ni)
        #pragma unroll
        for (int r = 0; r < 4; ++r)
            Lg[(quad * 4 + r) * 260 + wave * 64 + ni * 16 + lm] = acc[ni][r];
    __syncthreads();

    // ---- softmax (h = tid>>4, 16 threads/h over 16-key chunks) ----
    {
        int h = tid >> 4, j = tid & 15;
        float m = -INFINITY;
        #pragma unroll
        for (int kk = 0; kk < 16; ++kk) {
            int key = j * 16 + kk;
            if (kidx[key] <= t) m = fmaxf(m, Lg[h * 260 + key]);
        }
        red[h * 17 + j] = m;
        __syncthreads();
        float mh = -INFINITY;
        #pragma unroll
        for (int jj = 0; jj < 16; ++jj) mh = fmaxf(mh, red[h * 17 + jj]);
        __syncthreads();
        float s = 0.f;
        float pv[16];
        #pragma unroll
        for (int kk = 0; kk < 16; ++kk) {
            int key = j * 16 + kk;
            float e = (kidx[key] <= t) ? expf(Lg[h * 260 + key] * SCALE_LOG - mh * SCALE_LOG) : 0.f;
            pv[kk] = e; s += e;
        }
        red[h * 17 + j] = s;
        __syncthreads();
        float sh = 0.f;
        #pragma unroll
        for (int jj = 0; jj < 16; ++jj) sh += red[h * 17 + jj];
        float inv = 1.f / sh;
        #pragma unroll
        for (int kk = 0; kk < 16; ++kk)
            Pbf[h * 264 + j * 16 + kk] = f2bf(pv[kk] * inv);
    }
    __syncthreads();

    // ---- Phase B: out_latent ----
    const int kk2 = tid & 31, cquad = tid >> 5;  // kk2: key-in-step, cquad 0..7
    uint4 pf2[8];
    {
        const unsigned short* row = kvb + (long)kidx[kk2] * CKV_;
        #pragma unroll
        for (int rep = 0; rep < 8; ++rep)
            pf2[rep] = *(const uint4*)(row + rep * 64 + cquad * 8);
    }

    ffrag acc2[8];
    #pragma unroll
    for (int ci = 0; ci < 8; ++ci)
        #pragma unroll
        for (int r = 0; r < 4; ++r) acc2[ci][r] = 0.f;

    for (int k0 = 0; k0 < TOPK_; k0 += 32) {
        __syncthreads();
        #pragma unroll
        for (int rep = 0; rep < 8; ++rep) {
            int cu = rep * 8 + cquad;
            const unsigned short* us = (const unsigned short*)&pf2[rep];
            #pragma unroll
            for (int i = 0; i < 8; ++i)
                VT[(cu * 8 + i) * 36 + kk2] = us[i];
        }
        __syncthreads();
        if (k0 + 32 < TOPK_) {
            const unsigned short* row = kvb + (long)kidx[k0 + 32 + kk2] * CKV_;
            #pragma unroll
            for (int rep = 0; rep < 8; ++rep)
                pf2[rep] = *(const uint4*)(row + rep * 64 + cquad * 8);
        }
        bfrag pa = *(const bfrag*)(Pbf + lm * 264 + k0 + quad * 8);
        #pragma unroll
        for (int ci = 0; ci < 8; ++ci) {
            int c = wave * 128 + ci * 16 + lm;
            bfrag bv;
            ((uint2*)&bv)[0] = *(const uint2*)(VT + c * 36 + quad * 8);
            ((uint2*)&bv)[1] = *(const uint2*)(VT + c * 36 + quad * 8 + 4);
            acc2[ci] = __builtin_amdgcn_mfma_f32_16x16x32_bf16(pa, bv, acc2[ci], 0, 0, 0);
        }
    }
    // store olat bf16: [t*16 + h][512], h = quad*4+r, c = wave*128 + ci*16 + lm
    #pragma unroll
    for (int ci = 0; ci < 8; ++ci)
        #pragma unroll
        for (int r = 0; r < 4; ++r)
            olat[((long)t * H_ + quad * 4 + r) * 512 + wave * 128 + ci * 16 + lm] = f2bf(acc2[ci][r]);
}

// ---------------------------------------------------------------------------
extern "C" void kernel_launch(void* const* d_in, const int* in_sizes, int n_in,
                              void* d_out, int out_size, void* d_ws, size_t ws_size,
                              hipStream_t stream)
{
    const float* x          = (const float*)d_in[0];
    const float* cosb       = (const float*)d_in[1];
    const float* sinb       = (const float*)d_in[2];
    const float* wq_a       = (const float*)d_in[3];
    const float* q_norm_w   = (const float*)d_in[4];
    const float* wq_b       = (const float*)d_in[5];
    const float* wkv_a      = (const float*)d_in[6];
    const float* kv_norm_w  = (const float*)d_in[7];
    const float* wkv_b      = (const float*)d_in[8];
    const float* wo         = (const float*)d_in[9];
    const float* iq_norm_w  = (const float*)d_in[10];
    const float* iwq_b      = (const float*)d_in[11];
    const float* iwk        = (const float*)d_in[12];
    const float* k_norm_w   = (const float*)d_in[13];
    const float* k_norm_b   = (const float*)d_in[14];
    const float* wproj      = (const float*)d_in[15];
    float* out = (float*)d_out;

    // fp32 workspace (float offsets)
    float* ws    = (float*)d_ws;
    float* qr    = ws;                      // 1,048,576 (dead after qr casts -> kvb)
    float* rstd  = ws + 1048576;
    float* wtok  = ws + 1049600;
    float* kvkey = ws + 1065984;            // 589,824
    int*   topk  = (int*)(ws + 1655808);    // 262,144 ints
    float* qkey  = ws + 1917952;            // 9,437,184
    float* outv  = ws + 11355136;           // 2,097,152 (slot)
    float* U0    = ws + 13452288;           // union region
    float* iq    = U0;                      // 2,097,152
    float* ik    = U0 + 2097152;            // 2,097,152
    float* kva   = U0 + 4194304;            // 589,824
    float* qbuf  = U0 + 4784128;            // 3,145,728
    float* score = U0 + 7929856;            // 1,048,576

    // bf16 sublayouts (ushort units)
    unsigned short* qkey_u = (unsigned short*)qkey;      // free until qpe/qnope
    unsigned short* wqa_hi  = qkey_u;
    unsigned short* wqa_lo  = qkey_u + 2097152;
    unsigned short* iwk_hi  = qkey_u + 4194304;
    unsigned short* iwk_lo  = qkey_u + 8388608;
    unsigned short* iwqb_hi = qkey_u + 12582912;
    unsigned short* iwqb_lo = qkey_u + 14680064;
    unsigned short* qriq_hi = qkey_u + 16777216;
    unsigned short* qriq_lo = qkey_u + 17825792;
    // mid-phase: score bf16 inputs (over dead early casts)
    unsigned short* iqbf_hi = qkey_u;
    unsigned short* iqbf_lo = qkey_u + 2097152;
    unsigned short* ikbf_hi = qkey_u + 4194304;
    unsigned short* ikbf_lo = qkey_u + 6291456;
    // late-phase (qkey dead after attn3):
    unsigned short* wkvb_bf = qkey_u + 8388608;
    unsigned short* wo_bf   = qkey_u + 12582912;
    // q slot early reuse:
    unsigned short* q_u     = (unsigned short*)qbuf;
    unsigned short* x_hi    = q_u;
    unsigned short* x_lo    = q_u + 2097152;
    unsigned short* wkva_hi = q_u + 4194304;
    // outv slot early reuse:
    unsigned short* outv_u  = (unsigned short*)outv;
    unsigned short* wqb_hi  = outv_u;                    // dead after q GEMM
    unsigned short* qrq_hi  = outv_u + 3145728;
    unsigned short* outv_bf = outv_u;                    // outv GEMM writes bf16 here
    // iq / ik slots (dead after score3 input casts):
    unsigned short* qbf     = (unsigned short*)iq;
    unsigned short* wkT     = (unsigned short*)ik;
    // qr slot (dead after qriq/qrq casts): kvkey bf16
    unsigned short* kvb     = (unsigned short*)qr;
    // olat bf16 at U0 (iq+ik slots, dead after qnope GEMM)
    unsigned short* olat_bf = (unsigned short*)U0;       // 8,388,608 us

    #define CAST(src, hi, lo, n, cw, rs, K) \
        cast_hl_k<<<(n)/1024, 256, 0, stream>>>((src), (hi), (lo), (n), (cw), (rs), (K))

    // ---- casts (early) ----
    CAST(x,     x_hi,   x_lo,   2097152L, nullptr, nullptr, 0);
    CAST(wq_a,  wqa_hi, wqa_lo, 2097152L, nullptr, nullptr, 0);
    CAST(iwk,   iwk_hi, iwk_lo, 4194304L, nullptr, nullptr, 0);
    CAST(iwq_b, iwqb_hi,iwqb_lo,2097152L, nullptr, nullptr, 0);
    CAST(wkv_a, wkva_hi,nullptr,1179648L, nullptr, nullptr, 0);
    CAST(wq_b,  wqb_hi, nullptr,3145728L, nullptr, nullptr, 0);

    // ---- qr = x @ wq_a.T (fused bf16x3) ----
    gemm3_bt64_k<<<dim3(QLR_/64, T_/64), 256, 0, stream>>>(
        x_hi, x_lo, wqa_hi, wqa_lo, qr, DIM_, DIM_, QLR_, DIM_);

    rstd_k<<<T_, 256, 0, stream>>>(qr, rstd);
    CAST(qr, qriq_hi, qriq_lo, 1048576L, iq_norm_w, rstd, QLR_);
    CAST(qr, qrq_hi,  nullptr, 1048576L, q_norm_w,  rstd, QLR_);

    // ---- iq / ik (fused bf16x3) ----
    gemm3_bt64_k<<<dim3(IH_*ID_/64, T_/64), 256, 0, stream>>>(
        qriq_hi, qriq_lo, iwqb_hi, iwqb_lo, iq, QLR_, QLR_, IH_*ID_, QLR_);
    gemm3_bt64_k<<<dim3(IH_*ID_/64, T_/64), 256, 0, stream>>>(
        x_hi, x_lo, iwk_hi, iwk_lo, ik, DIM_, DIM_, IH_*ID_, DIM_);

    // ---- kva = x @ wkv_a.T (bf16, N=576 guarded) ----
    gemm_bt64_k<<<dim3((CKV_+63)/64, T_/64, 1), 256, 0, stream>>>(
        x_hi, wkva_hi, kva, 0,0,0, DIM_, DIM_, CKV_, CKV_, DIM_, 0);

    // ---- q = rmsnorm(qr,q_norm) @ wq_b.T (bf16) ----
    gemm_bt64_k<<<dim3(H_*QKD_/64, T_/64, 1), 256, 0, stream>>>(
        qrq_hi, wqb_hi, qbuf, 0,0,0, QLR_, QLR_, H_*QKD_, H_*QKD_, QLR_, 0);

    // ---- wtok ----
    wtok_k<<<T_, 256, 0, stream>>>(x, wproj, wtok);

    // ---- per-row transforms ----
    transform_iq_k<<<T_*IH_, 128, 0, stream>>>(iq, cosb, sinb);
    transform_ik_k<<<T_*IH_, 128, 0, stream>>>(ik, k_norm_w, k_norm_b, cosb, sinb);
    transform_kv_k<<<T_, 256, 0, stream>>>(kva, kvkey, kv_norm_w, cosb, sinb);

    // ---- kvkey -> bf16 (into dead qr slot) ----
    CAST(kvkey, kvb, nullptr, 589824L, nullptr, nullptr, 0);

    // ---- score bf16 hi/lo casts + score + topk ----
    CAST(iq, iqbf_hi, iqbf_lo, 2097152L, nullptr, nullptr, 0);
    CAST(ik, ikbf_hi, ikbf_lo, 2097152L, nullptr, nullptr, 0);
    score3_k<<<dim3(T_/64, T_/64), 256, 0, stream>>>(iqbf_hi, iqbf_lo, ikbf_hi, ikbf_lo, wtok, score);
    topk_k<<<T_, 512, 0, stream>>>(score, topk);

    // ---- q_key assembly (qkey fp32) ----
    CAST(qbuf, qbf, nullptr, 3145728L, nullptr, nullptr, 0);
    tcast_k<<<dim3(16, 4, 16), 256, 0, stream>>>(wkv_b, wkT);
    qpe_k<<<T_*H_/2, 64, 0, stream>>>(qbuf, qkey, cosb, sinb);
    gemm_bt_mfma_k<<<dim3(KVLR_/128, T_/128, H_), 256, 0, stream>>>(
        qbf, wkT, qkey, 192L, 65536L, 576L, H_*QKD_, ID_, H_*CKV_, KVLR_, ID_);

    // ---- attention (MFMA) -> olat bf16 @ U0 ----
    attn3_k<<<T_, 256, 0, stream>>>(qkey, kvb, topk, olat_bf);

    // ---- out_v = out_latent @ w_v^T (bf16 batched, bf16 out) ----
    CAST(wkv_b, wkvb_bf, nullptr, 2097152L, nullptr, nullptr, 0);   // qkey region now dead
    gemm_bt64_k<<<dim3(VD_/64, T_/64, H_), 256, 0, stream>>>(
        olat_bf, wkvb_bf + (long)NOPE_*KVLR_, outv_bf,
        512L, (long)(NOPE_+VD_)*KVLR_, (long)VD_,
        H_*KVLR_, KVLR_, H_*VD_, VD_, KVLR_, 1);

    // ---- out = outv @ wo.T (bf16) ----
    CAST(wo, wo_bf, nullptr, 4194304L, nullptr, nullptr, 0);
    gemm_bt64_k<<<dim3(DIM_/64, T_/64, 1), 256, 0, stream>>>(
        outv_bf, wo_bf, out, 0,0,0, H_*VD_, H_*VD_, DIM_, DIM_, H_*VD_, 0);

    #undef CAST
    (void)in_sizes; (void)n_in; (void)out_size; (void)ws_size;
}

// Round 7
// 601.260 us; speedup vs baseline: 1.0687x; 1.0687x over previous
//
#include <hip/hip_runtime.h>
#include <hip/hip_bf16.h>
#include <math.h>

// Problem constants
#define T_     1024
#define DIM_   2048
#define H_     16
#define QLR_   1024
#define KVLR_  512
#define NOPE_  128
#define ROPE_  64
#define VD_    128
#define QKD_   192   // NOPE+ROPE
#define IH_    16
#define ID_    128
#define TOPK_  256
#define CKV_   576   // KVLR + ROPE

#define SCALE_W    0.022097086912079608f   // IH^-0.5 * ID^-0.5
#define SCALE_LOG  0.07216878364870323f    // QKD^-0.5

typedef short bfrag __attribute__((ext_vector_type(8)));   // 8 bf16 = 4 VGPRs
typedef float ffrag __attribute__((ext_vector_type(4)));   // 4 fp32 acc

__device__ __forceinline__ unsigned short f2bf(float f) {
    union { __hip_bfloat16 h; unsigned short u; } c; c.h = __float2bfloat16(f); return c.u;
}
__device__ __forceinline__ float bf2f(unsigned short u) {
    union { unsigned short u; __hip_bfloat16 h; } c; c.u = u; return __bfloat162float(c.h);
}

// ---------------------------------------------------------------------------
// fp32 -> bf16 cast, optional hi/lo split and per-row/col scaling.
// ---------------------------------------------------------------------------
__global__ __launch_bounds__(256) void cast_hl_k(
    const float* __restrict__ in, unsigned short* __restrict__ hi,
    unsigned short* __restrict__ lo, long n,
    const float* __restrict__ colw, const float* __restrict__ rowscale, int Kc)
{
    long base = ((long)blockIdx.x * 256 + threadIdx.x) * 4;
    if (base >= n) return;
    float4 v = *(const float4*)(in + base);
    float s[4] = {v.x, v.y, v.z, v.w};
    if (colw) {
        int col = (int)(base % Kc);
        float4 cw = *(const float4*)(colw + col);
        s[0] *= cw.x; s[1] *= cw.y; s[2] *= cw.z; s[3] *= cw.w;
    }
    if (rowscale) {
        float r = rowscale[base / Kc];
        s[0] *= r; s[1] *= r; s[2] *= r; s[3] *= r;
    }
    ushort4 h4;
    h4.x = f2bf(s[0]); h4.y = f2bf(s[1]); h4.z = f2bf(s[2]); h4.w = f2bf(s[3]);
    *(ushort4*)(hi + base) = h4;
    if (lo) {
        ushort4 l4;
        l4.x = f2bf(s[0] - bf2f(h4.x));
        l4.y = f2bf(s[1] - bf2f(h4.y));
        l4.z = f2bf(s[2] - bf2f(h4.z));
        l4.w = f2bf(s[3] - bf2f(h4.w));
        *(ushort4*)(lo + base) = l4;
    }
}

// ---------------------------------------------------------------------------
// Transpose-cast w_k: wkT[h][c][d] = bf16(wkv_b[(h*256+d)*512 + c]), d<128, c<512
// ---------------------------------------------------------------------------
__global__ __launch_bounds__(256) void tcast_k(const float* __restrict__ in,
                                               unsigned short* __restrict__ out)
{
    int h = blockIdx.z, c0 = blockIdx.x * 32, d0 = blockIdx.y * 32;
    __shared__ float t[32][33];
    int tx = threadIdx.x & 31, ty = threadIdx.x >> 5;
    #pragma unroll
    for (int i = 0; i < 4; ++i)
        t[ty + i * 8][tx] = in[(long)(h * 256 + d0 + ty + i * 8) * 512 + c0 + tx];
    __syncthreads();
    #pragma unroll
    for (int i = 0; i < 4; ++i)
        out[((long)h * 512 + c0 + ty + i * 8) * 128 + d0 + tx] = f2bf(t[tx][ty + i * 8]);
}

// ---------------------------------------------------------------------------
// MFMA bf16 NT GEMM, 128x128 tile (batched q_nope_proj). Register-prefetch.
// ---------------------------------------------------------------------------
__global__ __launch_bounds__(256) void gemm_bt_mfma_k(
    const unsigned short* __restrict__ A, const unsigned short* __restrict__ B,
    float* __restrict__ C, long sA, long sB, long sC,
    int lda, int ldb, int ldc, int N, int K)
{
    A += (long)blockIdx.z * sA;
    B += (long)blockIdx.z * sB;
    C += (long)blockIdx.z * sC;
    __shared__ unsigned short As[128 * 40];
    __shared__ unsigned short Bs[128 * 40];
    const int tid = threadIdx.x;
    const int bm = blockIdx.y * 128, bn = blockIdx.x * 128;
    const int wave = tid >> 6, lane = tid & 63;
    const int wm = (wave >> 1) * 64, wn = (wave & 1) * 64;
    const int lm = lane & 15, quad = lane >> 4;

    ffrag acc[4][4];
    #pragma unroll
    for (int mi = 0; mi < 4; ++mi)
        #pragma unroll
        for (int ni = 0; ni < 4; ++ni)
            #pragma unroll
            for (int r = 0; r < 4; ++r) acc[mi][ni][r] = 0.f;

    const int srow = tid >> 1, shalf = tid & 1;
    const long aoff = (long)(bm + srow) * lda + shalf * 16;
    int brow = bn + srow; if (brow > N - 1) brow = N - 1;
    const long boff = (long)brow * ldb + shalf * 16;
    unsigned short* la = As + srow * 40 + shalf * 16;
    unsigned short* lb = Bs + srow * 40 + shalf * 16;

    uint4 va0 = *(const uint4*)(A + aoff);
    uint4 va1 = *(const uint4*)(A + aoff + 8);
    uint4 vb0 = *(const uint4*)(B + boff);
    uint4 vb1 = *(const uint4*)(B + boff + 8);

    for (int k0 = 0; k0 < K; k0 += 32) {
        __syncthreads();
        *(uint4*)la = va0; *(uint4*)(la + 8) = va1;
        *(uint4*)lb = vb0; *(uint4*)(lb + 8) = vb1;
        __syncthreads();
        if (k0 + 32 < K) {
            va0 = *(const uint4*)(A + aoff + k0 + 32);
            va1 = *(const uint4*)(A + aoff + k0 + 40);
            vb0 = *(const uint4*)(B + boff + k0 + 32);
            vb1 = *(const uint4*)(B + boff + k0 + 40);
        }
        bfrag af[4], bf[4];
        #pragma unroll
        for (int mi = 0; mi < 4; ++mi)
            af[mi] = *(const bfrag*)(As + (wm + mi * 16 + lm) * 40 + quad * 8);
        #pragma unroll
        for (int ni = 0; ni < 4; ++ni)
            bf[ni] = *(const bfrag*)(Bs + (wn + ni * 16 + lm) * 40 + quad * 8);
        #pragma unroll
        for (int mi = 0; mi < 4; ++mi)
            #pragma unroll
            for (int ni = 0; ni < 4; ++ni)
                acc[mi][ni] = __builtin_amdgcn_mfma_f32_16x16x32_bf16(
                    af[mi], bf[ni], acc[mi][ni], 0, 0, 0);
    }

    #pragma unroll
    for (int mi = 0; mi < 4; ++mi)
        #pragma unroll
        for (int ni = 0; ni < 4; ++ni) {
            int n = bn + wn + ni * 16 + lm;
            if (n < N) {
                int mb = bm + wm + mi * 16 + quad * 4;
                #pragma unroll
                for (int r = 0; r < 4; ++r)
                    C[(long)(mb + r) * ldc + n] = acc[mi][ni][r];
            }
        }
}

// ---------------------------------------------------------------------------
// MFMA bf16 NT GEMM, 64x64 tile. obf=1 -> write bf16 C. Register-prefetch.
// ---------------------------------------------------------------------------
__global__ __launch_bounds__(256) void gemm_bt64_k(
    const unsigned short* __restrict__ A, const unsigned short* __restrict__ B,
    void* __restrict__ Cv, long sA, long sB, long sC,
    int lda, int ldb, int ldc, int N, int K, int obf)
{
    A += (long)blockIdx.z * sA;
    B += (long)blockIdx.z * sB;
    __shared__ unsigned short As[64 * 40];
    __shared__ unsigned short Bs[64 * 40];
    const int tid = threadIdx.x;
    const int bm = blockIdx.y * 64, bn = blockIdx.x * 64;
    const int wave = tid >> 6, lane = tid & 63;
    const int wm = (wave >> 1) * 32, wn = (wave & 1) * 32;
    const int lm = lane & 15, quad = lane >> 4;

    ffrag acc[2][2];
    #pragma unroll
    for (int mi = 0; mi < 2; ++mi)
        #pragma unroll
        for (int ni = 0; ni < 2; ++ni)
            #pragma unroll
            for (int r = 0; r < 4; ++r) acc[mi][ni][r] = 0.f;

    const int srow = tid >> 2, schunk = tid & 3;
    const long aoff = (long)(bm + srow) * lda + schunk * 8;
    int brow = bn + srow; if (brow > N - 1) brow = N - 1;
    const long boff = (long)brow * ldb + schunk * 8;
    unsigned short* la = As + srow * 40 + schunk * 8;
    unsigned short* lb = Bs + srow * 40 + schunk * 8;

    uint4 va = *(const uint4*)(A + aoff);
    uint4 vb = *(const uint4*)(B + boff);

    for (int k0 = 0; k0 < K; k0 += 32) {
        __syncthreads();
        *(uint4*)la = va;
        *(uint4*)lb = vb;
        __syncthreads();
        if (k0 + 32 < K) {
            va = *(const uint4*)(A + aoff + k0 + 32);
            vb = *(const uint4*)(B + boff + k0 + 32);
        }
        bfrag af[2], bf[2];
        #pragma unroll
        for (int mi = 0; mi < 2; ++mi)
            af[mi] = *(const bfrag*)(As + (wm + mi * 16 + lm) * 40 + quad * 8);
        #pragma unroll
        for (int ni = 0; ni < 2; ++ni)
            bf[ni] = *(const bfrag*)(Bs + (wn + ni * 16 + lm) * 40 + quad * 8);
        #pragma unroll
        for (int mi = 0; mi < 2; ++mi)
            #pragma unroll
            for (int ni = 0; ni < 2; ++ni)
                acc[mi][ni] = __builtin_amdgcn_mfma_f32_16x16x32_bf16(
                    af[mi], bf[ni], acc[mi][ni], 0, 0, 0);
    }

    #pragma unroll
    for (int mi = 0; mi < 2; ++mi)
        #pragma unroll
        for (int ni = 0; ni < 2; ++ni) {
            int n = bn + wn + ni * 16 + lm;
            if (n < N) {
                int mb = bm + wm + mi * 16 + quad * 4;
                if (obf) {
                    unsigned short* C = (unsigned short*)Cv + (long)blockIdx.z * sC;
                    #pragma unroll
                    for (int r = 0; r < 4; ++r)
                        C[(long)(mb + r) * ldc + n] = f2bf(acc[mi][ni][r]);
                } else {
                    float* C = (float*)Cv + (long)blockIdx.z * sC;
                    #pragma unroll
                    for (int r = 0; r < 4; ++r)
                        C[(long)(mb + r) * ldc + n] = acc[mi][ni][r];
                }
            }
        }
}

// ---------------------------------------------------------------------------
// Fused bf16x3 NT GEMM, 64x64 tile: C = Ah.Bh^T + Ah.Bl^T + Al.Bh^T
// Register-prefetch pipelined.
// ---------------------------------------------------------------------------
__global__ __launch_bounds__(256) void gemm3_bt64_k(
    const unsigned short* __restrict__ Ah, const unsigned short* __restrict__ Al,
    const unsigned short* __restrict__ Bh, const unsigned short* __restrict__ Bl,
    float* __restrict__ C, int lda, int ldb, int ldc, int K)
{
    __shared__ unsigned short Ahs[64 * 40], Als[64 * 40], Bhs[64 * 40], Bls[64 * 40];
    const int tid = threadIdx.x;
    const int bm = blockIdx.y * 64, bn = blockIdx.x * 64;
    const int wave = tid >> 6, lane = tid & 63;
    const int wm = (wave >> 1) * 32, wn = (wave & 1) * 32;
    const int lm = lane & 15, quad = lane >> 4;

    ffrag acc[2][2];
    #pragma unroll
    for (int mi = 0; mi < 2; ++mi)
        #pragma unroll
        for (int ni = 0; ni < 2; ++ni)
            #pragma unroll
            for (int r = 0; r < 4; ++r) acc[mi][ni][r] = 0.f;

    const int srow = tid >> 2, schunk = tid & 3;
    const long aoff = (long)(bm + srow) * lda + schunk * 8;
    const long boff = (long)(bn + srow) * ldb + schunk * 8;
    const int loff = srow * 40 + schunk * 8;

    uint4 vah = *(const uint4*)(Ah + aoff);
    uint4 val = *(const uint4*)(Al + aoff);
    uint4 vbh = *(const uint4*)(Bh + boff);
    uint4 vbl = *(const uint4*)(Bl + boff);

    for (int k0 = 0; k0 < K; k0 += 32) {
        __syncthreads();
        *(uint4*)(Ahs + loff) = vah;
        *(uint4*)(Als + loff) = val;
        *(uint4*)(Bhs + loff) = vbh;
        *(uint4*)(Bls + loff) = vbl;
        __syncthreads();
        if (k0 + 32 < K) {
            vah = *(const uint4*)(Ah + aoff + k0 + 32);
            val = *(const uint4*)(Al + aoff + k0 + 32);
            vbh = *(const uint4*)(Bh + boff + k0 + 32);
            vbl = *(const uint4*)(Bl + boff + k0 + 32);
        }
        bfrag ah[2], al[2], bh[2], bl[2];
        #pragma unroll
        for (int mi = 0; mi < 2; ++mi) {
            ah[mi] = *(const bfrag*)(Ahs + (wm + mi * 16 + lm) * 40 + quad * 8);
            al[mi] = *(const bfrag*)(Als + (wm + mi * 16 + lm) * 40 + quad * 8);
        }
        #pragma unroll
        for (int ni = 0; ni < 2; ++ni) {
            bh[ni] = *(const bfrag*)(Bhs + (wn + ni * 16 + lm) * 40 + quad * 8);
            bl[ni] = *(const bfrag*)(Bls + (wn + ni * 16 + lm) * 40 + quad * 8);
        }
        #pragma unroll
        for (int mi = 0; mi < 2; ++mi)
            #pragma unroll
            for (int ni = 0; ni < 2; ++ni) {
                acc[mi][ni] = __builtin_amdgcn_mfma_f32_16x16x32_bf16(ah[mi], bh[ni], acc[mi][ni], 0, 0, 0);
                acc[mi][ni] = __builtin_amdgcn_mfma_f32_16x16x32_bf16(ah[mi], bl[ni], acc[mi][ni], 0, 0, 0);
                acc[mi][ni] = __builtin_amdgcn_mfma_f32_16x16x32_bf16(al[mi], bh[ni], acc[mi][ni], 0, 0, 0);
            }
    }

    #pragma unroll
    for (int mi = 0; mi < 2; ++mi)
        #pragma unroll
        for (int ni = 0; ni < 2; ++ni) {
            int n = bn + wn + ni * 16 + lm;
            int mb = bm + wm + mi * 16 + quad * 4;
            #pragma unroll
            for (int r = 0; r < 4; ++r)
                C[(long)(mb + r) * ldc + n] = acc[mi][ni][r];
        }
}

// ---------------------------------------------------------------------------
// Fused wtok: wtok[t,h] = dot(x[t,:], wproj[h,:]) * SCALE_W  (fp32)
// ---------------------------------------------------------------------------
__global__ __launch_bounds__(256) void wtok_k(const float* __restrict__ x,
    const float* __restrict__ wproj, float* __restrict__ wtok)
{
    int t = blockIdx.x, tid = threadIdx.x;
    __shared__ float xs[DIM_];
    for (int c = tid; c < DIM_; c += 256) xs[c] = x[(long)t * DIM_ + c];
    __syncthreads();
    int wave = tid >> 6, lane = tid & 63;
    #pragma unroll
    for (int i = 0; i < 4; ++i) {
        int h = wave * 4 + i;
        float s = 0.f;
        for (int c = lane; c < DIM_; c += 64) s += xs[c] * wproj[(long)h * DIM_ + c];
        for (int off = 32; off; off >>= 1) s += __shfl_xor(s, off, 64);
        if (lane == 0) wtok[(long)t * IH_ + h] = s * SCALE_W;
    }
}

// ---------------------------------------------------------------------------
__global__ __launch_bounds__(256) void rstd_k(const float* __restrict__ qr, float* __restrict__ rstd)
{
    int t = blockIdx.x, tid = threadIdx.x;
    float s = 0.f;
    for (int c = tid; c < QLR_; c += 256) { float v = qr[(long)t * QLR_ + c]; s += v * v; }
    __shared__ float red[256];
    red[tid] = s; __syncthreads();
    for (int off = 128; off; off >>= 1) { if (tid < off) red[tid] += red[tid + off]; __syncthreads(); }
    if (tid == 0) rstd[t] = rsqrtf(red[0] / (float)QLR_ + 1e-6f);
}

// ---------------------------------------------------------------------------
__device__ __forceinline__ void rope_rotate_128(float* s, float* w2, int tid, int t,
    const float* __restrict__ cosb, const float* __restrict__ sinb)
{
    float n1 = 0.f, n2 = 0.f;
    if (tid < 32) {
        float x1 = s[tid], x2 = s[tid + 32];
        float c = cosb[t * 32 + tid], sn = sinb[t * 32 + tid];
        n1 = x1 * c - x2 * sn;
        n2 = x1 * sn + x2 * c;
    }
    __syncthreads();
    if (tid < 32) { s[tid] = n1; s[tid + 32] = n2; }
    __syncthreads();
    const int g = tid >> 6, p = tid & 63;
    w2[tid] = s[((1 - g) << 6) + p];
    __syncthreads();
    #pragma unroll
    for (int h = 1; h < 64; h <<= 1) {
        float a = w2[tid], b = w2[(g << 6) + (p ^ h)];
        __syncthreads();
        w2[tid] = (p & h) ? (b - a) : (a + b);
        __syncthreads();
    }
}

__global__ __launch_bounds__(128) void transform_iq_k(float* __restrict__ iq,
    const float* __restrict__ cosb, const float* __restrict__ sinb)
{
    int row = blockIdx.x;
    int t = row / IH_;
    int tid = threadIdx.x;
    __shared__ float s[128], w2[128];
    s[tid] = iq[(long)row * 128 + tid];
    __syncthreads();
    rope_rotate_128(s, w2, tid, t, cosb, sinb);
    iq[(long)row * 128 + tid] = w2[tid];
}

__global__ __launch_bounds__(128) void transform_ik_k(float* __restrict__ ik,
    const float* __restrict__ knw, const float* __restrict__ knb,
    const float* __restrict__ cosb, const float* __restrict__ sinb)
{
    int row = blockIdx.x;
    int t = row / IH_;
    int tid = threadIdx.x;
    __shared__ float s[128], w2[128], red[128];
    float v = ik[(long)row * 128 + tid];
    red[tid] = v; __syncthreads();
    for (int off = 64; off; off >>= 1) { if (tid < off) red[tid] += red[tid + off]; __syncthreads(); }
    float m = red[0] / 128.f; __syncthreads();
    float d = v - m;
    red[tid] = d * d; __syncthreads();
    for (int off = 64; off; off >>= 1) { if (tid < off) red[tid] += red[tid + off]; __syncthreads(); }
    float var = red[0] / 128.f;
    s[tid] = d * rsqrtf(var + 1e-5f) * knw[tid] + knb[tid];
    __syncthreads();
    rope_rotate_128(s, w2, tid, t, cosb, sinb);
    ik[(long)row * 128 + tid] = w2[tid];
}

__global__ __launch_bounds__(256) void transform_kv_k(const float* __restrict__ kva,
    float* __restrict__ kvkey, const float* __restrict__ kvnw,
    const float* __restrict__ cosb, const float* __restrict__ sinb)
{
    int t = blockIdx.x, tid = threadIdx.x;
    const float* a = kva + (long)t * CKV_;
    float* o = kvkey + (long)t * CKV_;
    float v0 = a[tid], v1 = a[tid + 256];
    __shared__ float red[256];
    __shared__ float rsh;
    red[tid] = v0 * v0 + v1 * v1; __syncthreads();
    for (int off = 128; off; off >>= 1) { if (tid < off) red[tid] += red[tid + off]; __syncthreads(); }
    if (tid == 0) rsh = rsqrtf(red[0] / (float)KVLR_ + 1e-6f);
    __syncthreads();
    float rs = rsh;
    o[tid]       = v0 * rs * kvnw[tid];
    o[tid + 256] = v1 * rs * kvnw[tid + 256];
    if (tid < 32) {
        float x1 = a[512 + tid], x2 = a[544 + tid];
        float c = cosb[t * 32 + tid], sn = sinb[t * 32 + tid];
        o[512 + tid] = x1 * c - x2 * sn;
        o[544 + tid] = x1 * sn + x2 * c;
    }
}

__global__ __launch_bounds__(64) void qpe_k(const float* __restrict__ q, float* __restrict__ qkey,
    const float* __restrict__ cosb, const float* __restrict__ sinb)
{
    int row = blockIdx.x * 2 + (threadIdx.x >> 5);
    int i = threadIdx.x & 31;
    int t = row / H_;
    const float* qp = q + (long)row * QKD_ + NOPE_;
    float x1 = qp[i], x2 = qp[i + 32];
    float c = cosb[t * 32 + i], sn = sinb[t * 32 + i];
    float* o = qkey + (long)row * CKV_ + 512;
    o[i]      = x1 * c - x2 * sn;
    o[i + 32] = x1 * sn + x2 * c;
}

// ---------------------------------------------------------------------------
// Indexer score (MFMA bf16x3), register-prefetch across (h,k0) steps.
// ---------------------------------------------------------------------------
__global__ __launch_bounds__(256) void score3_k(
    const unsigned short* __restrict__ iqh, const unsigned short* __restrict__ iql,
    const unsigned short* __restrict__ ikh, const unsigned short* __restrict__ ikl,
    const float* __restrict__ wtok, float* __restrict__ score)
{
    const int bt = blockIdx.y, bs = blockIdx.x;
    if (bs > bt) return;
    __shared__ unsigned short Ah[64 * 40], Al[64 * 40], Bh[64 * 40], Bl[64 * 40];
    __shared__ float wts[64][16];
    const int tid = threadIdx.x;
    const int wave = tid >> 6, lane = tid & 63;
    const int wm = (wave >> 1) * 32, wn = (wave & 1) * 32;
    const int lm = lane & 15, quad = lane >> 4;
    const int t0 = bt * 64, s0 = bs * 64;
    const int srow = tid >> 2, schunk = tid & 3;
    const int loff = srow * 40 + schunk * 8;

    for (int e = tid; e < 1024; e += 256)
        wts[e >> 4][e & 15] = wtok[(long)(t0 + (e >> 4)) * IH_ + (e & 15)];

    const long abase = (long)(t0 + srow) * 2048 + schunk * 8;
    const long bbase = (long)(s0 + srow) * 2048 + schunk * 8;

    uint4 pah = *(const uint4*)(iqh + abase);
    uint4 pal = *(const uint4*)(iql + abase);
    uint4 pbh = *(const uint4*)(ikh + bbase);
    uint4 pbl = *(const uint4*)(ikl + bbase);

    float accf[2][2][4] = {};

    for (int h = 0; h < IH_; ++h) {
        ffrag acch[2][2];
        #pragma unroll
        for (int mi = 0; mi < 2; ++mi)
            #pragma unroll
            for (int ni = 0; ni < 2; ++ni)
                #pragma unroll
                for (int r = 0; r < 4; ++r) acch[mi][ni][r] = 0.f;

        #pragma unroll
        for (int k0 = 0; k0 < ID_; k0 += 32) {
            __syncthreads();
            *(uint4*)(Ah + loff) = pah;
            *(uint4*)(Al + loff) = pal;
            *(uint4*)(Bh + loff) = pbh;
            *(uint4*)(Bl + loff) = pbl;
            __syncthreads();
            int step = h * 4 + (k0 >> 5) + 1;
            if (step < 64) {
                int off = (step >> 2) * 128 + (step & 3) * 32;
                pah = *(const uint4*)(iqh + abase + off);
                pal = *(const uint4*)(iql + abase + off);
                pbh = *(const uint4*)(ikh + bbase + off);
                pbl = *(const uint4*)(ikl + bbase + off);
            }
            bfrag ahf[2], alf[2], bhf[2], blf[2];
            #pragma unroll
            for (int mi = 0; mi < 2; ++mi) {
                ahf[mi] = *(const bfrag*)(Ah + (wm + mi * 16 + lm) * 40 + quad * 8);
                alf[mi] = *(const bfrag*)(Al + (wm + mi * 16 + lm) * 40 + quad * 8);
            }
            #pragma unroll
            for (int ni = 0; ni < 2; ++ni) {
                bhf[ni] = *(const bfrag*)(Bh + (wn + ni * 16 + lm) * 40 + quad * 8);
                blf[ni] = *(const bfrag*)(Bl + (wn + ni * 16 + lm) * 40 + quad * 8);
            }
            #pragma unroll
            for (int mi = 0; mi < 2; ++mi)
                #pragma unroll
                for (int ni = 0; ni < 2; ++ni) {
                    acch[mi][ni] = __builtin_amdgcn_mfma_f32_16x16x32_bf16(ahf[mi], bhf[ni], acch[mi][ni], 0, 0, 0);
                    acch[mi][ni] = __builtin_amdgcn_mfma_f32_16x16x32_bf16(ahf[mi], blf[ni], acch[mi][ni], 0, 0, 0);
                    acch[mi][ni] = __builtin_amdgcn_mfma_f32_16x16x32_bf16(alf[mi], bhf[ni], acch[mi][ni], 0, 0, 0);
                }
        }
        #pragma unroll
        for (int mi = 0; mi < 2; ++mi) {
            float wr[4];
            #pragma unroll
            for (int r = 0; r < 4; ++r) wr[r] = wts[wm + mi * 16 + quad * 4 + r][h];
            #pragma unroll
            for (int ni = 0; ni < 2; ++ni)
                #pragma unroll
                for (int r = 0; r < 4; ++r)
                    accf[mi][ni][r] += fmaxf(acch[mi][ni][r], 0.f) * wr[r];
        }
    }
    #pragma unroll
    for (int mi = 0; mi < 2; ++mi)
        #pragma unroll
        for (int ni = 0; ni < 2; ++ni) {
            int s = s0 + wn + ni * 16 + lm;
            int tb = t0 + wm + mi * 16 + quad * 4;
            #pragma unroll
            for (int r = 0; r < 4; ++r)
                score[(long)(tb + r) * T_ + s] = accf[mi][ni][r];
        }
}

// ---------------------------------------------------------------------------
// Top-256 per row via bitonic sort (ties -> lower index, matches jax top_k)
// ---------------------------------------------------------------------------
__global__ __launch_bounds__(512) void topk_k(const float* __restrict__ score, int* __restrict__ topk)
{
    int t = blockIdx.x, tid = threadIdx.x;
    __shared__ float v[1024];
    __shared__ int ix[1024];
    for (int i = tid; i < 1024; i += 512) {
        v[i] = (i <= t) ? score[(long)t * T_ + i] : -INFINITY;
        ix[i] = i;
    }
    __syncthreads();
    for (int k = 2; k <= 1024; k <<= 1) {
        for (int j = k >> 1; j > 0; j >>= 1) {
            for (int i = tid; i < 1024; i += 512) {
                int l = i ^ j;
                if (l > i) {
                    bool up = ((i & k) == 0);
                    float vi = v[i], vl = v[l];
                    int xi = ix[i], xl = ix[l];
                    bool iBetter = (vi > vl) || (vi == vl && xi < xl);
                    bool doSwap = up ? !iBetter : iBetter;
                    if (doSwap) { v[i] = vl; v[l] = vi; ix[i] = xl; ix[l] = xi; }
                }
            }
            __syncthreads();
        }
    }
    if (tid < 256) topk[(long)t * TOPK_ + tid] = ix[tid];
}

// ---------------------------------------------------------------------------
// Attention v5 (MFMA bf16): one block per token, 4 waves, ~49.8 KB LDS
// (3 blocks/CU). NO cross-barrier register prefetch (r6 spilled to scratch:
// WRITE_SIZE 16->48 MB). Phase-B transpose uses paired-key b32 stores
// (256/thread vs 512 b16).
// LDS (ushort offsets): Qbf[16*584]@0; SelA[256*40]@9344 (Lg fp32 [16*260]
// overlays after phase A); Pbf[16*264]@19584; VT[512*36]@0 (phase B).
// ---------------------------------------------------------------------------
__global__ __launch_bounds__(256) void attn3_k(
    const float* __restrict__ qkey, const unsigned short* __restrict__ kvb,
    const int* __restrict__ topkp, unsigned short* __restrict__ olat)
{
    __shared__ unsigned short U[23808];
    __shared__ float red[16 * 17];
    __shared__ int kidx[256];
    unsigned short* Qbf  = U;                    // [16][584]
    unsigned short* SelA = U + 9344;             // [256][40]
    float*          Lg   = (float*)(U + 9344);   // [16][260] (after phase A)
    unsigned short* Pbf  = U + 19584;            // [16][264]
    unsigned short* VT   = U;                    // [512][36] (phase B)

    const int t = blockIdx.x, tid = threadIdx.x;
    const int wave = tid >> 6, lane = tid & 63;
    const int lm = lane & 15, quad = lane >> 4;

    kidx[tid] = topkp[(long)t * TOPK_ + tid];
    // stage + cast Q row: 9216 floats -> Qbf[16][584]
    const float4* q4 = (const float4*)(qkey + (long)t * (H_ * CKV_));
    #pragma unroll
    for (int rep = 0; rep < 9; ++rep) {
        int e4 = rep * 256 + tid;
        float4 v = q4[e4];
        int f = e4 * 4, h = f / CKV_, c = f - h * CKV_;
        ushort4 u4; u4.x = f2bf(v.x); u4.y = f2bf(v.y); u4.z = f2bf(v.z); u4.w = f2bf(v.w);
        *(ushort4*)(Qbf + h * 584 + c) = u4;
    }
    __syncthreads();

    // ---- Phase A: logits ----
    const int ukey = tid >> 2, uoff = (tid & 3) * 8;
    int myk[4];
    #pragma unroll
    for (int rep = 0; rep < 4; ++rep) myk[rep] = kidx[rep * 64 + ukey];

    ffrag acc[4];
    #pragma unroll
    for (int ni = 0; ni < 4; ++ni)
        #pragma unroll
        for (int r = 0; r < 4; ++r) acc[ni][r] = 0.f;

    for (int c0 = 0; c0 < CKV_; c0 += 32) {
        __syncthreads();
        #pragma unroll
        for (int rep = 0; rep < 4; ++rep) {
            uint4 v = *(const uint4*)(kvb + (long)myk[rep] * CKV_ + c0 + uoff);
            *(uint4*)(SelA + (rep * 64 + ukey) * 40 + uoff) = v;
        }
        __syncthreads();
        bfrag af = *(const bfrag*)(Qbf + lm * 584 + c0 + quad * 8);
        #pragma unroll
        for (int ni = 0; ni < 4; ++ni) {
            bfrag bf = *(const bfrag*)(SelA + (wave * 64 + ni * 16 + lm) * 40 + quad * 8);
            acc[ni] = __builtin_amdgcn_mfma_f32_16x16x32_bf16(af, bf, acc[ni], 0, 0, 0);
        }
    }
    __syncthreads();
    // write logits (overlays SelA): D col=lane&15 (key), row=quad*4+r (head)
    #pragma unroll
    for (int ni = 0; ni < 4; ++ni)
        #pragma unroll
        for (int r = 0; r < 4; ++r)
            Lg[(quad * 4 + r) * 260 + wave * 64 + ni * 16 + lm] = acc[ni][r];
    __syncthreads();

    // ---- softmax (h = tid>>4, 16 threads/h over 16-key chunks) ----
    {
        int h = tid >> 4, j = tid & 15;
        float m = -INFINITY;
        #pragma unroll
        for (int kk = 0; kk < 16; ++kk) {
            int key = j * 16 + kk;
            if (kidx[key] <= t) m = fmaxf(m, Lg[h * 260 + key]);
        }
        red[h * 17 + j] = m;
        __syncthreads();
        float mh = -INFINITY;
        #pragma unroll
        for (int jj = 0; jj < 16; ++jj) mh = fmaxf(mh, red[h * 17 + jj]);
        __syncthreads();
        float s = 0.f;
        float pv[16];
        #pragma unroll
        for (int kk = 0; kk < 16; ++kk) {
            int key = j * 16 + kk;
            float e = (kidx[key] <= t) ? expf(Lg[h * 260 + key] * SCALE_LOG - mh * SCALE_LOG) : 0.f;
            pv[kk] = e; s += e;
        }
        red[h * 17 + j] = s;
        __syncthreads();
        float sh = 0.f;
        #pragma unroll
        for (int jj = 0; jj < 16; ++jj) sh += red[h * 17 + jj];
        float inv = 1.f / sh;
        #pragma unroll
        for (int kk = 0; kk < 16; ++kk)
            Pbf[h * 264 + j * 16 + kk] = f2bf(pv[kk] * inv);
    }
    __syncthreads();

    // ---- Phase B: out_latent (paired-key b32 transpose stores) ----
    const int kp = tid & 15, cg = tid >> 4;   // kp: key pair, cg: 32-c group
    ffrag acc2[8];
    #pragma unroll
    for (int ci = 0; ci < 8; ++ci)
        #pragma unroll
        for (int r = 0; r < 4; ++r) acc2[ci][r] = 0.f;

    for (int k0 = 0; k0 < TOPK_; k0 += 32) {
        __syncthreads();
        {
            int ka = kidx[k0 + 2 * kp], kb = kidx[k0 + 2 * kp + 1];
            const unsigned short* ra = kvb + (long)ka * CKV_ + cg * 32;
            const unsigned short* rb = kvb + (long)kb * CKV_ + cg * 32;
            #pragma unroll
            for (int half = 0; half < 2; ++half) {
                uint4 a0 = *(const uint4*)(ra + half * 16);
                uint4 a1 = *(const uint4*)(ra + half * 16 + 8);
                uint4 b0 = *(const uint4*)(rb + half * 16);
                uint4 b1 = *(const uint4*)(rb + half * 16 + 8);
                const unsigned short* pa_ = (const unsigned short*)&a0;
                const unsigned short* pb_ = (const unsigned short*)&b0;
                #pragma unroll
                for (int i = 0; i < 8; ++i) {
                    int c = cg * 32 + half * 16 + i;
                    *(unsigned int*)(VT + c * 36 + 2 * kp) =
                        (unsigned int)pa_[i] | ((unsigned int)pb_[i] << 16);
                }
                pa_ = (const unsigned short*)&a1;
                pb_ = (const unsigned short*)&b1;
                #pragma unroll
                for (int i = 0; i < 8; ++i) {
                    int c = cg * 32 + half * 16 + 8 + i;
                    *(unsigned int*)(VT + c * 36 + 2 * kp) =
                        (unsigned int)pa_[i] | ((unsigned int)pb_[i] << 16);
                }
            }
        }
        __syncthreads();
        bfrag pa = *(const bfrag*)(Pbf + lm * 264 + k0 + quad * 8);
        #pragma unroll
        for (int ci = 0; ci < 8; ++ci) {
            int c = wave * 128 + ci * 16 + lm;
            bfrag bv;
            ((uint2*)&bv)[0] = *(const uint2*)(VT + c * 36 + quad * 8);
            ((uint2*)&bv)[1] = *(const uint2*)(VT + c * 36 + quad * 8 + 4);
            acc2[ci] = __builtin_amdgcn_mfma_f32_16x16x32_bf16(pa, bv, acc2[ci], 0, 0, 0);
        }
    }
    // store olat bf16: [t*16 + h][512], h = quad*4+r, c = wave*128 + ci*16 + lm
    #pragma unroll
    for (int ci = 0; ci < 8; ++ci)
        #pragma unroll
        for (int r = 0; r < 4; ++r)
            olat[((long)t * H_ + quad * 4 + r) * 512 + wave * 128 + ci * 16 + lm] = f2bf(acc2[ci][r]);
}

// ---------------------------------------------------------------------------
extern "C" void kernel_launch(void* const* d_in, const int* in_sizes, int n_in,
                              void* d_out, int out_size, void* d_ws, size_t ws_size,
                              hipStream_t stream)
{
    const float* x          = (const float*)d_in[0];
    const float* cosb       = (const float*)d_in[1];
    const float* sinb       = (const float*)d_in[2];
    const float* wq_a       = (const float*)d_in[3];
    const float* q_norm_w   = (const float*)d_in[4];
    const float* wq_b       = (const float*)d_in[5];
    const float* wkv_a      = (const float*)d_in[6];
    const float* kv_norm_w  = (const float*)d_in[7];
    const float* wkv_b      = (const float*)d_in[8];
    const float* wo         = (const float*)d_in[9];
    const float* iq_norm_w  = (const float*)d_in[10];
    const float* iwq_b      = (const float*)d_in[11];
    const float* iwk        = (const float*)d_in[12];
    const float* k_norm_w   = (const float*)d_in[13];
    const float* k_norm_b   = (const float*)d_in[14];
    const float* wproj      = (const float*)d_in[15];
    float* out = (float*)d_out;

    // fp32 workspace (float offsets)
    float* ws    = (float*)d_ws;
    float* qr    = ws;                      // 1,048,576 (dead after qr casts -> kvb)
    float* rstd  = ws + 1048576;
    float* wtok  = ws + 1049600;
    float* kvkey = ws + 1065984;            // 589,824
    int*   topk  = (int*)(ws + 1655808);    // 262,144 ints
    float* qkey  = ws + 1917952;            // 9,437,184
    float* outv  = ws + 11355136;           // 2,097,152 (slot)
    float* U0    = ws + 13452288;           // union region
    float* iq    = U0;                      // 2,097,152
    float* ik    = U0 + 2097152;            // 2,097,152
    float* kva   = U0 + 4194304;            // 589,824
    float* qbuf  = U0 + 4784128;            // 3,145,728
    float* score = U0 + 7929856;            // 1,048,576

    // bf16 sublayouts (ushort units)
    unsigned short* qkey_u = (unsigned short*)qkey;      // free until qpe/qnope
    unsigned short* wqa_hi  = qkey_u;
    unsigned short* wqa_lo  = qkey_u + 2097152;
    unsigned short* iwk_hi  = qkey_u + 4194304;
    unsigned short* iwk_lo  = qkey_u + 8388608;
    unsigned short* iwqb_hi = qkey_u + 12582912;
    unsigned short* iwqb_lo = qkey_u + 14680064;
    unsigned short* qriq_hi = qkey_u + 16777216;
    unsigned short* qriq_lo = qkey_u + 17825792;
    // mid-phase: score bf16 inputs (over dead early casts)
    unsigned short* iqbf_hi = qkey_u;
    unsigned short* iqbf_lo = qkey_u + 2097152;
    unsigned short* ikbf_hi = qkey_u + 4194304;
    unsigned short* ikbf_lo = qkey_u + 6291456;
    // late-phase (qkey dead after attn3):
    unsigned short* wkvb_bf = qkey_u + 8388608;
    unsigned short* wo_bf   = qkey_u + 12582912;
    // q slot early reuse:
    unsigned short* q_u     = (unsigned short*)qbuf;
    unsigned short* x_hi    = q_u;
    unsigned short* x_lo    = q_u + 2097152;
    unsigned short* wkva_hi = q_u + 4194304;
    // outv slot early reuse:
    unsigned short* outv_u  = (unsigned short*)outv;
    unsigned short* wqb_hi  = outv_u;                    // dead after q GEMM
    unsigned short* qrq_hi  = outv_u + 3145728;
    unsigned short* outv_bf = outv_u;                    // outv GEMM writes bf16 here
    // iq / ik slots (dead after score3 input casts):
    unsigned short* qbf     = (unsigned short*)iq;
    unsigned short* wkT     = (unsigned short*)ik;
    // qr slot (dead after qriq/qrq casts): kvkey bf16
    unsigned short* kvb     = (unsigned short*)qr;
    // olat bf16 at U0 (iq+ik slots, dead after qnope GEMM)
    unsigned short* olat_bf = (unsigned short*)U0;       // 8,388,608 us

    #define CAST(src, hi, lo, n, cw, rs, K) \
        cast_hl_k<<<(n)/1024, 256, 0, stream>>>((src), (hi), (lo), (n), (cw), (rs), (K))

    // ---- casts (early) ----
    CAST(x,     x_hi,   x_lo,   2097152L, nullptr, nullptr, 0);
    CAST(wq_a,  wqa_hi, wqa_lo, 2097152L, nullptr, nullptr, 0);
    CAST(iwk,   iwk_hi, iwk_lo, 4194304L, nullptr, nullptr, 0);
    CAST(iwq_b, iwqb_hi,iwqb_lo,2097152L, nullptr, nullptr, 0);
    CAST(wkv_a, wkva_hi,nullptr,1179648L, nullptr, nullptr, 0);
    CAST(wq_b,  wqb_hi, nullptr,3145728L, nullptr, nullptr, 0);

    // ---- qr = x @ wq_a.T (fused bf16x3) ----
    gemm3_bt64_k<<<dim3(QLR_/64, T_/64), 256, 0, stream>>>(
        x_hi, x_lo, wqa_hi, wqa_lo, qr, DIM_, DIM_, QLR_, DIM_);

    rstd_k<<<T_, 256, 0, stream>>>(qr, rstd);
    CAST(qr, qriq_hi, qriq_lo, 1048576L, iq_norm_w, rstd, QLR_);
    CAST(qr, qrq_hi,  nullptr, 1048576L, q_norm_w,  rstd, QLR_);

    // ---- iq / ik (fused bf16x3) ----
    gemm3_bt64_k<<<dim3(IH_*ID_/64, T_/64), 256, 0, stream>>>(
        qriq_hi, qriq_lo, iwqb_hi, iwqb_lo, iq, QLR_, QLR_, IH_*ID_, QLR_);
    gemm3_bt64_k<<<dim3(IH_*ID_/64, T_/64), 256, 0, stream>>>(
        x_hi, x_lo, iwk_hi, iwk_lo, ik, DIM_, DIM_, IH_*ID_, DIM_);

    // ---- kva = x @ wkv_a.T (bf16, N=576 guarded) ----
    gemm_bt64_k<<<dim3((CKV_+63)/64, T_/64, 1), 256, 0, stream>>>(
        x_hi, wkva_hi, kva, 0,0,0, DIM_, DIM_, CKV_, CKV_, DIM_, 0);

    // ---- q = rmsnorm(qr,q_norm) @ wq_b.T (bf16) ----
    gemm_bt64_k<<<dim3(H_*QKD_/64, T_/64, 1), 256, 0, stream>>>(
        qrq_hi, wqb_hi, qbuf, 0,0,0, QLR_, QLR_, H_*QKD_, H_*QKD_, QLR_, 0);

    // ---- wtok ----
    wtok_k<<<T_, 256, 0, stream>>>(x, wproj, wtok);

    // ---- per-row transforms ----
    transform_iq_k<<<T_*IH_, 128, 0, stream>>>(iq, cosb, sinb);
    transform_ik_k<<<T_*IH_, 128, 0, stream>>>(ik, k_norm_w, k_norm_b, cosb, sinb);
    transform_kv_k<<<T_, 256, 0, stream>>>(kva, kvkey, kv_norm_w, cosb, sinb);

    // ---- kvkey -> bf16 (into dead qr slot) ----
    CAST(kvkey, kvb, nullptr, 589824L, nullptr, nullptr, 0);

    // ---- score bf16 hi/lo casts + score + topk ----
    CAST(iq, iqbf_hi, iqbf_lo, 2097152L, nullptr, nullptr, 0);
    CAST(ik, ikbf_hi, ikbf_lo, 2097152L, nullptr, nullptr, 0);
    score3_k<<<dim3(T_/64, T_/64), 256, 0, stream>>>(iqbf_hi, iqbf_lo, ikbf_hi, ikbf_lo, wtok, score);
    topk_k<<<T_, 512, 0, stream>>>(score, topk);

    // ---- q_key assembly (qkey fp32) ----
    CAST(qbuf, qbf, nullptr, 3145728L, nullptr, nullptr, 0);
    tcast_k<<<dim3(16, 4, 16), 256, 0, stream>>>(wkv_b, wkT);
    qpe_k<<<T_*H_/2, 64, 0, stream>>>(qbuf, qkey, cosb, sinb);
    gemm_bt_mfma_k<<<dim3(KVLR_/128, T_/128, H_), 256, 0, stream>>>(
        qbf, wkT, qkey, 192L, 65536L, 576L, H_*QKD_, ID_, H_*CKV_, KVLR_, ID_);

    // ---- attention (MFMA) -> olat bf16 @ U0 ----
    attn3_k<<<T_, 256, 0, stream>>>(qkey, kvb, topk, olat_bf);

    // ---- out_v = out_latent @ w_v^T (bf16 batched, bf16 out) ----
    CAST(wkv_b, wkvb_bf, nullptr, 2097152L, nullptr, nullptr, 0);   // qkey region now dead
    gemm_bt64_k<<<dim3(VD_/64, T_/64, H_), 256, 0, stream>>>(
        olat_bf, wkvb_bf + (long)NOPE_*KVLR_, outv_bf,
        512L, (long)(NOPE_+VD_)*KVLR_, (long)VD_,
        H_*KVLR_, KVLR_, H_*VD_, VD_, KVLR_, 1);

    // ---- out = outv @ wo.T (bf16) ----
    CAST(wo, wo_bf, nullptr, 4194304L, nullptr, nullptr, 0);
    gemm_bt64_k<<<dim3(DIM_/64, T_/64, 1), 256, 0, stream>>>(
        outv_bf, wo_bf, out, 0,0,0, H_*VD_, H_*VD_, DIM_, DIM_, H_*VD_, 0);

    #undef CAST
    (void)in_sizes; (void)n_in; (void)out_size; (void)ws_size;
}